// Round 3
// baseline (438.082 us; speedup 1.0000x reference)
//
#include <hip/hip_runtime.h>
#include <math.h>

#define B_  8
#define S_  8192
#define D_  64
#define H_  8
#define NB_ 128     // buckets per hash round
#define NC_ 1024    // chunks per batch (H_*NB_)
#define REP_CAP 65536

typedef _Float16 f16x8 __attribute__((ext_vector_type(8)));
typedef _Float16 f16x2 __attribute__((ext_vector_type(2)));
typedef float    f32x4 __attribute__((ext_vector_type(4)));
typedef float    f32x2 __attribute__((ext_vector_type(2)));

// ---------------------------------------------------------------------------
// Kernel 0: zero the repair counter (ws is poisoned 0xAA before every launch).
// ---------------------------------------------------------------------------
__global__ void init_kernel(int* cnt) { *cnt = 0; }

// ---------------------------------------------------------------------------
// Kernel 1: LSH hash, fp32 main pass (packed FMA), 2 tokens/thread, with
// provable top-2 gap test. Tokens whose max/min/cross margin < T2 are flagged
// for exact fp64 repair. Bucket results are bit-identical to the fp64 kernel.
// fp32 dot error bound: 64*2^-24*||q||*||r_i|| ~ 5e-4;  T2 = 4e-3 (>= 4x).
// ---------------------------------------------------------------------------
__global__ __launch_bounds__(256) void hash_kernel(
    const float* __restrict__ qk, const float* __restrict__ rot,
    int* __restrict__ bucket, int* __restrict__ cnt, int2* __restrict__ list)
{
  __shared__ float rotT[64 * 64];             // [f][i] fp32, 16 KB
  const int tid  = threadIdx.x;
  const int tile = blockIdx.x & 15;           // 16 tiles of 512 tokens
  const int bh   = blockIdx.x >> 4;           // b*8 + h
  const int h    = bh & 7;
  const int b    = bh >> 3;

  {                                           // stage rot slice for this h
    const int f = tid >> 2, q4 = tid & 3;
    const float4* src = (const float4*)(rot + f * 512 + h * 64 + q4 * 16);
    float4* dst = (float4*)(rotT + f * 64 + q4 * 16);
#pragma unroll
    for (int k = 0; k < 4; ++k) dst[k] = src[k];
  }
  __syncthreads();

  const int t0 = tile * 512 + tid;            // two tokens per thread
  const int t1 = t0 + 256;
  float qa[64], qb[64];
  {
    const float4* s0 = (const float4*)(qk + ((size_t)b * S_ + t0) * D_);
    const float4* s1 = (const float4*)(qk + ((size_t)b * S_ + t1) * D_);
#pragma unroll
    for (int k = 0; k < 16; ++k) { ((float4*)qa)[k] = s0[k]; ((float4*)qb)[k] = s1[k]; }
  }

  // top-2 state per token: max side (v1,v2,idx) and min side
  float v1M[2] = {-1e30f, -1e30f}, v2M[2] = {-1e30f, -1e30f};
  float v1m[2] = { 1e30f,  1e30f}, v2m[2] = { 1e30f,  1e30f};
  int   iM[2]  = {0, 0},          im[2]  = {0, 0};

#pragma unroll 1
  for (int i0 = 0; i0 < 64; i0 += 8) {
    f32x2 a0[4], a1[4];
#pragma unroll
    for (int k = 0; k < 4; ++k) { a0[k] = (f32x2){0.f, 0.f}; a1[k] = (f32x2){0.f, 0.f}; }
#pragma unroll
    for (int f = 0; f < 64; ++f) {
      const float4 R0 = *(const float4*)(rotT + f * 64 + i0);      // ds_read_b128
      const float4 R1 = *(const float4*)(rotT + f * 64 + i0 + 4);  // ds_read_b128
      const f32x2 r0 = {R0.x, R0.y}, r1 = {R0.z, R0.w};
      const f32x2 r2 = {R1.x, R1.y}, r3 = {R1.z, R1.w};
      const f32x2 xv = {qa[f], qa[f]};
      const f32x2 yv = {qb[f], qb[f]};
      a0[0] += xv * r0; a0[1] += xv * r1; a0[2] += xv * r2; a0[3] += xv * r3;
      a1[0] += yv * r0; a1[1] += yv * r1; a1[2] += yv * r2; a1[3] += yv * r3;
    }
    // top-2 update, 8 values per token, index order preserved (first-max)
#pragma unroll
    for (int a = 0; a < 8; ++a) {
      const int idx = i0 + a;
      {
        const float x = a0[a >> 1][a & 1];
        const bool gM = x > v1M[0];
        v2M[0] = gM ? v1M[0] : fmaxf(v2M[0], x);
        iM[0]  = gM ? idx : iM[0];
        v1M[0] = gM ? x : v1M[0];
        const bool lm = x < v1m[0];
        v2m[0] = lm ? v1m[0] : fminf(v2m[0], x);
        im[0]  = lm ? idx : im[0];
        v1m[0] = lm ? x : v1m[0];
      }
      {
        const float x = a1[a >> 1][a & 1];
        const bool gM = x > v1M[1];
        v2M[1] = gM ? v1M[1] : fmaxf(v2M[1], x);
        iM[1]  = gM ? idx : iM[1];
        v1M[1] = gM ? x : v1M[1];
        const bool lm = x < v1m[1];
        v2m[1] = lm ? v1m[1] : fminf(v2m[1], x);
        im[1]  = lm ? idx : im[1];
        v1m[1] = lm ? x : v1m[1];
      }
    }
  }

  const float T2 = 4e-3f;
  const int tt[2] = {t0, t1};
#pragma unroll
  for (int z = 0; z < 2; ++z) {
    const int bkt = (v1M[z] >= -v1m[z]) ? iM[z] : 64 + im[z];
    bucket[(size_t)bh * S_ + tt[z]] = bkt;
    const bool flag = ((v1M[z] - v2M[z]) < T2) | ((v2m[z] - v1m[z]) < T2) |
                      (fabsf(v1M[z] + v1m[z]) < T2);
    if (flag) {
      const int s = atomicAdd(cnt, 1);
      if (s < REP_CAP) list[s] = make_int2(bh, tt[z]);
    }
  }
}

// ---------------------------------------------------------------------------
// Kernel 1b: exact fp64 repair for flagged tokens. One wave per token; lane i
// computes rotated[i] in fp64, butterfly arg-reduce with lowest-index ties.
// ---------------------------------------------------------------------------
__global__ __launch_bounds__(256) void repair_kernel(
    const float* __restrict__ qk, const float* __restrict__ rot,
    const int* __restrict__ cnt, const int2* __restrict__ list,
    int* __restrict__ bucket)
{
  const int n = min(*cnt, REP_CAP);
  const int lane = threadIdx.x & 63;
  const int wid  = (blockIdx.x * 256 + threadIdx.x) >> 6;
  const int nw   = gridDim.x * 4;
  for (int idx = wid; idx < n; idx += nw) {
    const int bh = list[idx].x, t = list[idx].y;
    const int b = bh >> 3, hh = bh & 7;
    const float* qrow = qk + ((size_t)b * S_ + t) * D_;
    const float* rcol = rot + hh * 64 + lane;
    double acc = 0.0;
#pragma unroll 8
    for (int f = 0; f < 64; ++f)
      acc = fma((double)qrow[f], (double)rcol[(size_t)f * 512], acc);

    double vM = acc; int iM = lane;
    double vm = acc; int im = lane;
#pragma unroll
    for (int off = 32; off >= 1; off >>= 1) {
      const double voM = __shfl_xor(vM, off); const int ioM = __shfl_xor(iM, off);
      if (voM > vM || (voM == vM && ioM < iM)) { vM = voM; iM = ioM; }
      const double vom = __shfl_xor(vm, off); const int iom = __shfl_xor(im, off);
      if (vom < vm || (vom == vm && iom < im)) { vm = vom; im = iom; }
    }
    if (lane == 0) {
      const int bkt = (vM >= -vm) ? iM : 64 + im;
      bucket[(size_t)bh * S_ + t] = bkt;
    }
  }
}

// ---------------------------------------------------------------------------
// Kernel 2: stable counting sort per (b,h). Unchanged.
// ---------------------------------------------------------------------------
__global__ __launch_bounds__(1024) void sort_kernel(
    const int* __restrict__ bucket, int* __restrict__ st,
    int* __restrict__ undo)
{
  __shared__ int lb[S_];
  __shared__ int hist[8 * 128];
  __shared__ int off[128];
  const int tid = threadIdx.x;
  const int bh  = blockIdx.x;
  const size_t base = (size_t)bh * S_;

  for (int k = tid; k < S_; k += 1024) lb[k] = bucket[base + k];
  hist[tid] = 0;
  __syncthreads();

  {
    const int seg = tid >> 7;
    const int t0 = tid * 8;
#pragma unroll
    for (int k = 0; k < 8; ++k) atomicAdd(&hist[seg * 128 + lb[t0 + k]], 1);
  }
  __syncthreads();
  if (tid < 128) {
    int s = 0;
#pragma unroll
    for (int g = 0; g < 8; ++g) s += hist[g * 128 + tid];
    off[tid] = s;
  }
  __syncthreads();
  if (tid == 0) {
    int run = 0;
    for (int k = 0; k < 128; ++k) { const int c = off[k]; off[k] = run; run += c; }
  }
  __syncthreads();
  if (tid < 128) {
    int run = off[tid];
#pragma unroll
    for (int g = 0; g < 8; ++g) { const int c = hist[g * 128 + tid]; hist[g * 128 + tid] = run; run += c; }
  }
  __syncthreads();

  const int bkt = tid & 127;
  const int seg = tid >> 7;
  int pos = hist[seg * 128 + bkt];
  const int sbase = seg * 1024;
  const int b = bh >> 3, h = bh & 7;
  const size_t stb = (size_t)b * (H_ * S_) + (size_t)h * S_;
  for (int k = 0; k < 1024; ++k) {
    const int t = sbase + k;
    if (lb[t] == bkt) {
      st[stb + pos] = t;
      undo[base + t] = h * S_ + pos;
      ++pos;
    }
  }
}

// ---------------------------------------------------------------------------
// Kernel 3: bucketed attention via f16 MFMA. Unchanged from R2.
// ---------------------------------------------------------------------------
__global__ __launch_bounds__(256, 4) void attn_kernel(
    const float* __restrict__ qk, const float* __restrict__ v,
    const int* __restrict__ st, float* __restrict__ so,
    float* __restrict__ slogits)
{
  __shared__ _Float16 sQ[64 * 72];    // 9216 B
  __shared__ _Float16 sK[64 * 72];    // 9216 B
  __shared__ _Float16 sP[64 * 136];   // 17408 B
  __shared__ int sIds[128];

  const int tid = threadIdx.x;
  const int c   = blockIdx.x & (NC_ - 1);
  const int b   = blockIdx.x >> 10;
  const int cm1 = (c + NC_ - 1) & (NC_ - 1);
  const size_t bst = (size_t)b * (H_ * S_);
  const size_t row0 = bst + (size_t)c * 64;
  const size_t row1 = bst + (size_t)cm1 * 64;

  const int lane = tid & 63;
  const int w    = tid >> 6;
  const int m16  = lane & 15;
  const int qd   = lane >> 4;

  if (tid < 128) sIds[tid] = (tid < 64) ? st[row0 + tid] : st[row1 + tid - 64];

  const int r  = tid >> 2, qu = tid & 3;
  {
    const int tok = st[row0 + r];
    const f32x4* src = (const f32x4*)(qk + ((size_t)b * S_ + tok) * D_ + qu * 16);
    float x[16];
#pragma unroll
    for (int k = 0; k < 4; ++k) ((f32x4*)x)[k] = src[k];
    float ss = 0.f;
#pragma unroll
    for (int k = 0; k < 16; ++k) ss = fmaf(x[k], x[k], ss);
    ss += __shfl_xor(ss, 1); ss += __shfl_xor(ss, 2);
    const float inv = 0.125f / (sqrtf(ss) + 1e-6f);
    f16x8 raw0, raw1, nrm0, nrm1;
#pragma unroll
    for (int jj = 0; jj < 8; ++jj) {
      raw0[jj] = (_Float16)x[jj];         raw1[jj] = (_Float16)x[jj + 8];
      nrm0[jj] = (_Float16)(x[jj] * inv); nrm1[jj] = (_Float16)(x[jj + 8] * inv);
    }
    *(f16x8*)(sQ + r * 72 + qu * 16)     = raw0;
    *(f16x8*)(sQ + r * 72 + qu * 16 + 8) = raw1;
    *(f16x8*)(sK + r * 72 + qu * 16)     = nrm0;
    *(f16x8*)(sK + r * 72 + qu * 16 + 8) = nrm1;
  }
  __syncthreads();

  f32x4 acc[8];
#pragma unroll
  for (int jt = 0; jt < 8; ++jt) acc[jt] = (f32x4){0.f, 0.f, 0.f, 0.f};

  const _Float16* qrow = sQ + (16 * w + m16) * 72;
  const f16x8 a0 = *(const f16x8*)(qrow + 8 * qd);
  const f16x8 a1 = *(const f16x8*)(qrow + 32 + 8 * qd);

#pragma unroll
  for (int jt = 0; jt < 4; ++jt) {
    const _Float16* krow = sK + (16 * jt + m16) * 72;
    const f16x8 b0 = *(const f16x8*)(krow + 8 * qd);
    const f16x8 b1 = *(const f16x8*)(krow + 32 + 8 * qd);
    acc[jt] = __builtin_amdgcn_mfma_f32_16x16x32_f16(a0, b0, acc[jt], 0, 0, 0);
    acc[jt] = __builtin_amdgcn_mfma_f32_16x16x32_f16(a1, b1, acc[jt], 0, 0, 0);
  }
  __syncthreads();

  {
    const int tok = st[row1 + r];
    const f32x4* src = (const f32x4*)(qk + ((size_t)b * S_ + tok) * D_ + qu * 16);
    float x[16];
#pragma unroll
    for (int k = 0; k < 4; ++k) ((f32x4*)x)[k] = src[k];
    float ss = 0.f;
#pragma unroll
    for (int k = 0; k < 16; ++k) ss = fmaf(x[k], x[k], ss);
    ss += __shfl_xor(ss, 1); ss += __shfl_xor(ss, 2);
    const float inv = 0.125f / (sqrtf(ss) + 1e-6f);
    f16x8 nrm0, nrm1;
#pragma unroll
    for (int jj = 0; jj < 8; ++jj) {
      nrm0[jj] = (_Float16)(x[jj] * inv); nrm1[jj] = (_Float16)(x[jj + 8] * inv);
    }
    *(f16x8*)(sK + r * 72 + qu * 16)     = nrm0;
    *(f16x8*)(sK + r * 72 + qu * 16 + 8) = nrm1;
  }
  __syncthreads();

#pragma unroll
  for (int jt = 4; jt < 8; ++jt) {
    const _Float16* krow = sK + (16 * (jt - 4) + m16) * 72;
    const f16x8 b0 = *(const f16x8*)(krow + 8 * qd);
    const f16x8 b1 = *(const f16x8*)(krow + 32 + 8 * qd);
    acc[jt] = __builtin_amdgcn_mfma_f32_16x16x32_f16(a0, b0, acc[jt], 0, 0, 0);
    acc[jt] = __builtin_amdgcn_mfma_f32_16x16x32_f16(a1, b1, acc[jt], 0, 0, 0);
  }

  const int jp = tid >> 2;
  const int tok0 = sIds[2 * jp], tok1 = sIds[2 * jp + 1];
  f32x4 vr0[4], vr1[4];
  {
    const f32x4* s0 = (const f32x4*)(v + ((size_t)b * S_ + tok0) * D_ + qu * 16);
    const f32x4* s1 = (const f32x4*)(v + ((size_t)b * S_ + tok1) * D_ + qu * 16);
#pragma unroll
    for (int k = 0; k < 4; ++k) { vr0[k] = s0[k]; vr1[k] = s1[k]; }
  }

  int rid[4];
#pragma unroll
  for (int rg = 0; rg < 4; ++rg) rid[rg] = sIds[16 * w + 4 * qd + rg];
  float rmax[4] = {-1e30f, -1e30f, -1e30f, -1e30f};
#pragma unroll
  for (int jt = 0; jt < 8; ++jt) {
    const int cid = sIds[16 * jt + m16];
#pragma unroll
    for (int rg = 0; rg < 4; ++rg) {
      float x = acc[jt][rg];
      if (rid[rg] == cid) x = -5e4f;
      acc[jt][rg] = x;
      rmax[rg] = fmaxf(rmax[rg], x);
    }
  }
#pragma unroll
  for (int rg = 0; rg < 4; ++rg) {
    rmax[rg] = fmaxf(rmax[rg], __shfl_xor(rmax[rg], 1));
    rmax[rg] = fmaxf(rmax[rg], __shfl_xor(rmax[rg], 2));
    rmax[rg] = fmaxf(rmax[rg], __shfl_xor(rmax[rg], 4));
    rmax[rg] = fmaxf(rmax[rg], __shfl_xor(rmax[rg], 8));
  }
  float rsum[4] = {0.f, 0.f, 0.f, 0.f};
#pragma unroll
  for (int jt = 0; jt < 8; ++jt)
#pragma unroll
    for (int rg = 0; rg < 4; ++rg) {
      const float e = __expf(acc[jt][rg] - rmax[rg]);
      acc[jt][rg] = e;
      rsum[rg] += e;
    }
#pragma unroll
  for (int rg = 0; rg < 4; ++rg) {
    rsum[rg] += __shfl_xor(rsum[rg], 1);
    rsum[rg] += __shfl_xor(rsum[rg], 2);
    rsum[rg] += __shfl_xor(rsum[rg], 4);
    rsum[rg] += __shfl_xor(rsum[rg], 8);
  }
  float rinv[4];
#pragma unroll
  for (int rg = 0; rg < 4; ++rg) rinv[rg] = 1.f / rsum[rg];
  if (m16 == 0) {
#pragma unroll
    for (int rg = 0; rg < 4; ++rg)
      slogits[row0 + 16 * w + 4 * qd + rg] = rmax[rg] + __logf(rsum[rg]);
  }

#pragma unroll
  for (int jt = 0; jt < 8; ++jt)
#pragma unroll
    for (int rg = 0; rg < 4; ++rg)
      sP[(16 * w + 4 * qd + rg) * 136 + 16 * jt + m16] = (_Float16)acc[jt][rg];

  __syncthreads();

  {
    const int j = 2 * jp;
    _Float16* dst = (j < 64) ? (sK + (j)) : (sQ + (j - 64));
    float x0[16], x1[16];
#pragma unroll
    for (int k = 0; k < 4; ++k) { ((f32x4*)x0)[k] = vr0[k]; ((f32x4*)x1)[k] = vr1[k]; }
#pragma unroll
    for (int jj = 0; jj < 16; ++jj) {
      const int d = qu * 16 + jj;
      f16x2 pk; pk[0] = (_Float16)x0[jj]; pk[1] = (_Float16)x1[jj];
      *(f16x2*)(dst + d * 72) = pk;
    }
  }
  __syncthreads();

  f32x4 oacc[4];
#pragma unroll
  for (int dt = 0; dt < 4; ++dt) oacc[dt] = (f32x4){0.f, 0.f, 0.f, 0.f};

  const _Float16* prow = sP + (16 * w + m16) * 136;
#pragma unroll
  for (int s = 0; s < 4; ++s) {
    const f16x8 ap = *(const f16x8*)(prow + 32 * s + 8 * qd);
    const _Float16* vbase = (s < 2) ? sK : sQ;
    const int col0 = 32 * (s & 1) + 8 * qd;
#pragma unroll
    for (int dt = 0; dt < 4; ++dt) {
      const f16x8 bv = *(const f16x8*)(vbase + (16 * dt + m16) * 72 + col0);
      oacc[dt] = __builtin_amdgcn_mfma_f32_16x16x32_f16(ap, bv, oacc[dt], 0, 0, 0);
    }
  }

  const size_t ob = row0 * 64;
#pragma unroll
  for (int dt = 0; dt < 4; ++dt)
#pragma unroll
    for (int rg = 0; rg < 4; ++rg) {
      const int i = 16 * w + 4 * qd + rg;
      const int d = 16 * dt + m16;
      so[ob + (size_t)i * 64 + d] = oacc[dt][rg] * rinv[rg];
    }
}

// ---------------------------------------------------------------------------
// Kernel 4: un-sort + combine rounds with logsumexp weights. Unchanged.
// ---------------------------------------------------------------------------
__global__ __launch_bounds__(256) void combine_kernel(
    const float* __restrict__ so, const float* __restrict__ slogits,
    const int* __restrict__ undo, float* __restrict__ out)
{
  const int gt = blockIdx.x * 4 + (threadIdx.x >> 6);
  const int d  = threadIdx.x & 63;
  const int b  = gt >> 13;
  const int t  = gt & (S_ - 1);
  const size_t bst = (size_t)b * (H_ * S_);

  int p[8]; float l[8];
#pragma unroll
  for (int h = 0; h < 8; ++h) {
    p[h] = undo[((size_t)b * 8 + h) * S_ + t];
    l[h] = slogits[bst + p[h]];
  }
  float m = l[0];
#pragma unroll
  for (int h = 1; h < 8; ++h) m = fmaxf(m, l[h]);
  float wv[8], W = 0.f;
#pragma unroll
  for (int h = 0; h < 8; ++h) { wv[h] = expf(l[h] - m); W += wv[h]; }
  const float iW = 1.f / W;
  float acc = 0.f;
#pragma unroll
  for (int h = 0; h < 8; ++h)
    acc = fmaf(wv[h], so[(bst + (size_t)p[h]) * 64 + d], acc);
  out[(size_t)gt * 64 + d] = acc * iW;
}

// ---------------------------------------------------------------------------
extern "C" void kernel_launch(void* const* d_in, const int* in_sizes, int n_in,
                              void* d_out, int out_size, void* d_ws, size_t ws_size,
                              hipStream_t stream)
{
  const float* qk  = (const float*)d_in[0];
  const float* v   = (const float*)d_in[1];
  const float* rot = (const float*)d_in[2];
  float* out = (float*)d_out;

  char* ws = (char*)d_ws;
  const size_t MB = 1ull << 20;
  int*   bucket = (int*)  (ws + 0 * MB);
  int*   st     = (int*)  (ws + 2 * MB);
  int*   undo   = (int*)  (ws + 4 * MB);
  float* slog   = (float*)(ws + 6 * MB);
  float* so     = (float*)(ws + 8 * MB);
  // repair state lives in the head of the so-region: dead once attn runs
  int*   cnt    = (int*)  (ws + 8 * MB);
  int2*  list   = (int2*) (ws + 8 * MB + 256);
  if (ws_size < 136 * MB) return;

  hipLaunchKernelGGL(init_kernel,    dim3(1),           dim3(1),    0, stream, cnt);
  hipLaunchKernelGGL(hash_kernel,    dim3(64 * 16),     dim3(256),  0, stream, qk, rot, bucket, cnt, list);
  hipLaunchKernelGGL(repair_kernel,  dim3(128),         dim3(256),  0, stream, qk, rot, cnt, list, bucket);
  hipLaunchKernelGGL(sort_kernel,    dim3(64),          dim3(1024), 0, stream, bucket, st, undo);
  hipLaunchKernelGGL(attn_kernel,    dim3(B_ * NC_),    dim3(256),  0, stream, qk, v, st, so, slog);
  hipLaunchKernelGGL(combine_kernel, dim3(B_ * S_ / 4), dim3(256),  0, stream, so, slog, undo, out);
}

// Round 4
// 288.894 us; speedup vs baseline: 1.5164x; 1.5164x over previous
//
#include <hip/hip_runtime.h>
#include <math.h>

#define B_  8
#define S_  8192
#define D_  64
#define H_  8
#define NB_ 128     // buckets per hash round
#define NC_ 1024    // chunks per batch (H_*NB_)
#define REP_CAP 65536
#define T2_ 2e-3f   // margin >= 4x the split-f16 worst-case error bound (~5e-4)

typedef _Float16 f16x8 __attribute__((ext_vector_type(8)));
typedef _Float16 f16x2 __attribute__((ext_vector_type(2)));
typedef float    f32x4 __attribute__((ext_vector_type(4)));

// ---------------------------------------------------------------------------
// Kernel 0: prep — zero repair counter; transpose+split rot into ws:
// rotHi/rotLo[h][i][f] f16 (i = rotation index, f contiguous -> A-fragment-ready)
// ---------------------------------------------------------------------------
__global__ __launch_bounds__(256) void prep_kernel(
    const float* __restrict__ rot, _Float16* __restrict__ rotHi,
    _Float16* __restrict__ rotLo, int* __restrict__ cnt)
{
  __shared__ float rs[64 * 64];               // [f][i]
  const int tid = threadIdx.x, h = blockIdx.x;
  if (h == 0 && tid == 0) *cnt = 0;
#pragma unroll
  for (int it = 0; it < 16; ++it) {
    const int f = it * 4 + (tid >> 6), i = tid & 63;
    rs[f * 64 + i] = rot[f * 512 + h * 64 + i];   // coalesced over i
  }
  __syncthreads();
  const int i = tid & 63, grp = tid >> 6;     // thread: row i, f-range 16grp..
  _Float16 hi[16], lo[16];
#pragma unroll
  for (int ff = 0; ff < 16; ++ff) {
    const float x = rs[(grp * 16 + ff) * 64 + i];
    hi[ff] = (_Float16)x;
    lo[ff] = (_Float16)(x - (float)hi[ff]);
  }
  f16x8* dH = (f16x8*)(rotHi + h * 4096 + i * 64 + grp * 16);
  f16x8* dL = (f16x8*)(rotLo + h * 4096 + i * 64 + grp * 16);
  dH[0] = ((f16x8*)hi)[0]; dH[1] = ((f16x8*)hi)[1];
  dL[0] = ((f16x8*)lo)[0]; dL[1] = ((f16x8*)lo)[1];
}

// ---------------------------------------------------------------------------
// Kernel 1: LSH hash via split-f16 MFMA. Block = (b,h) x 64 tokens.
// D[i][token] = rot^T x q: A-frag rows = i (from rotHi/Lo), B-frag rows = token.
// Lane (m16,qd) holds 16 i-values of token 16w+m16 -> in-register top-2 scan
// + 2 shuffle merges (xor 16/32). Margins < T2 -> flagged for fp64 repair.
// ---------------------------------------------------------------------------
__global__ __launch_bounds__(256) void hash_kernel(
    const float* __restrict__ qk, const _Float16* __restrict__ rotHi,
    const _Float16* __restrict__ rotLo,
    int* __restrict__ bucket, int* __restrict__ cnt, int2* __restrict__ list)
{
  __shared__ _Float16 qh[64 * 72];            // 9216 B each
  __shared__ _Float16 ql[64 * 72];
  __shared__ _Float16 rh[64 * 72];
  __shared__ _Float16 rl[64 * 72];
  const int tid  = threadIdx.x;
  const int tile = blockIdx.x & 127;
  const int bh   = blockIdx.x >> 7;
  const int h    = bh & 7, b = bh >> 3;
  const int t0   = tile * 64;

  {                                           // stage rot: clean b128 copies
    const int i = tid & 63, sel = tid >> 6;   // sel0/1: hi half, sel2/3: lo half
    const _Float16* src = ((sel & 2) ? rotLo : rotHi) + h * 4096 + i * 64 + (sel & 1) * 32;
    _Float16* dst = ((sel & 2) ? rl : rh) + i * 72 + (sel & 1) * 32;
#pragma unroll
    for (int k = 0; k < 4; ++k) ((f16x8*)dst)[k] = ((const f16x8*)src)[k];
  }
  {                                           // stage q: split hi/lo
    const int r = tid >> 2, qu = tid & 3;
    const float4* src = (const float4*)(qk + ((size_t)b * S_ + t0 + r) * D_ + qu * 16);
    float x[16];
#pragma unroll
    for (int k = 0; k < 4; ++k) ((float4*)x)[k] = src[k];
    f16x8 xh[2], xl[2];
#pragma unroll
    for (int j = 0; j < 16; ++j) {
      const _Float16 hi = (_Float16)x[j];
      xh[j >> 3][j & 7] = hi;
      xl[j >> 3][j & 7] = (_Float16)(x[j] - (float)hi);
    }
    *(f16x8*)(qh + r * 72 + qu * 16)     = xh[0];
    *(f16x8*)(qh + r * 72 + qu * 16 + 8) = xh[1];
    *(f16x8*)(ql + r * 72 + qu * 16)     = xl[0];
    *(f16x8*)(ql + r * 72 + qu * 16 + 8) = xl[1];
  }
  __syncthreads();

  const int lane = tid & 63, w = tid >> 6;
  const int m16 = lane & 15, qd = lane >> 4;

  // B-frags: token row = 16w + m16, k-chunk = 8*qd (+32 for half1)
  const _Float16* qrh = qh + (16 * w + m16) * 72;
  const _Float16* qrl = ql + (16 * w + m16) * 72;
  const f16x8 bh0 = *(const f16x8*)(qrh + 8 * qd);
  const f16x8 bh1 = *(const f16x8*)(qrh + 32 + 8 * qd);
  const f16x8 bl0 = *(const f16x8*)(qrl + 8 * qd);
  const f16x8 bl1 = *(const f16x8*)(qrl + 32 + 8 * qd);

  f32x4 acc[4];
#pragma unroll
  for (int mt = 0; mt < 4; ++mt) acc[mt] = (f32x4){0.f, 0.f, 0.f, 0.f};
#pragma unroll
  for (int mt = 0; mt < 4; ++mt) {            // A-frags: i row = 16mt + m16
    const _Float16* rrh = rh + (16 * mt + m16) * 72;
    const _Float16* rrl = rl + (16 * mt + m16) * 72;
    const f16x8 ah0 = *(const f16x8*)(rrh + 8 * qd);
    const f16x8 ah1 = *(const f16x8*)(rrh + 32 + 8 * qd);
    const f16x8 al0 = *(const f16x8*)(rrl + 8 * qd);
    const f16x8 al1 = *(const f16x8*)(rrl + 32 + 8 * qd);
    acc[mt] = __builtin_amdgcn_mfma_f32_16x16x32_f16(ah0, bh0, acc[mt], 0, 0, 0);
    acc[mt] = __builtin_amdgcn_mfma_f32_16x16x32_f16(ah1, bh1, acc[mt], 0, 0, 0);
    acc[mt] = __builtin_amdgcn_mfma_f32_16x16x32_f16(ah0, bl0, acc[mt], 0, 0, 0);
    acc[mt] = __builtin_amdgcn_mfma_f32_16x16x32_f16(ah1, bl1, acc[mt], 0, 0, 0);
    acc[mt] = __builtin_amdgcn_mfma_f32_16x16x32_f16(al0, bh0, acc[mt], 0, 0, 0);
    acc[mt] = __builtin_amdgcn_mfma_f32_16x16x32_f16(al1, bh1, acc[mt], 0, 0, 0);
  }

  // lane holds R[i = 16mt + 4qd + rg][token = 16w + m16]; ascending-i scan
  float v1M = -1e30f, v2M = -1e30f, v1m = 1e30f, v2m = 1e30f;
  int i1M = 0, i1m = 0;
#pragma unroll
  for (int mt = 0; mt < 4; ++mt)
#pragma unroll
    for (int rg = 0; rg < 4; ++rg) {
      const float x = acc[mt][rg];
      const int ix = 16 * mt + 4 * qd + rg;
      if (x > v1M) { v2M = v1M; v1M = x; i1M = ix; } else v2M = fmaxf(v2M, x);
      if (x < v1m) { v2m = v1m; v1m = x; i1m = ix; } else v2m = fminf(v2m, x);
    }
#pragma unroll
  for (int off = 16; off <= 32; off <<= 1) {  // merge the 4 qd-lanes per token
    const float ov1M = __shfl_xor(v1M, off), ov2M = __shfl_xor(v2M, off);
    const int   oi1M = __shfl_xor(i1M, off);
    if (ov1M > v1M) { v2M = fmaxf(v1M, ov2M); v1M = ov1M; i1M = oi1M; }
    else            { v2M = fmaxf(v2M, ov1M); }
    const float ov1m = __shfl_xor(v1m, off), ov2m = __shfl_xor(v2m, off);
    const int   oi1m = __shfl_xor(i1m, off);
    if (ov1m < v1m) { v2m = fminf(v1m, ov2m); v1m = ov1m; i1m = oi1m; }
    else            { v2m = fminf(v2m, ov1m); }
  }
  if (qd == 0) {
    const int t = t0 + 16 * w + m16;
    const int bkt = (v1M >= -v1m) ? i1M : 64 + i1m;
    bucket[(size_t)bh * S_ + t] = bkt;
    const bool flag = ((v1M - v2M) < T2_) | ((v2m - v1m) < T2_) |
                      (fabsf(v1M + v1m) < T2_);
    if (flag) {
      const int s = atomicAdd(cnt, 1);
      if (s < REP_CAP) list[s] = make_int2(bh, t);
    }
  }
}

// ---------------------------------------------------------------------------
// Kernel 1b: exact fp64 repair for flagged tokens. One wave per token.
// ---------------------------------------------------------------------------
__global__ __launch_bounds__(256) void repair_kernel(
    const float* __restrict__ qk, const float* __restrict__ rot,
    const int* __restrict__ cnt, const int2* __restrict__ list,
    int* __restrict__ bucket)
{
  const int n = min(*cnt, REP_CAP);
  const int lane = threadIdx.x & 63;
  const int wid  = (blockIdx.x * 256 + threadIdx.x) >> 6;
  const int nw   = gridDim.x * 4;
  for (int idx = wid; idx < n; idx += nw) {
    const int bh = list[idx].x, t = list[idx].y;
    const int b = bh >> 3, hh = bh & 7;
    const float* qrow = qk + ((size_t)b * S_ + t) * D_;
    const float* rcol = rot + hh * 64 + lane;
    double acc = 0.0;
#pragma unroll 8
    for (int f = 0; f < 64; ++f)
      acc = fma((double)qrow[f], (double)rcol[(size_t)f * 512], acc);

    double vM = acc; int iM = lane;
    double vm = acc; int im = lane;
#pragma unroll
    for (int off = 32; off >= 1; off >>= 1) {
      const double voM = __shfl_xor(vM, off); const int ioM = __shfl_xor(iM, off);
      if (voM > vM || (voM == vM && ioM < iM)) { vM = voM; iM = ioM; }
      const double vom = __shfl_xor(vm, off); const int iom = __shfl_xor(im, off);
      if (vom < vm || (vom == vm && iom < im)) { vm = vom; im = iom; }
    }
    if (lane == 0) {
      const int bkt = (vM >= -vm) ? iM : 64 + im;
      bucket[(size_t)bh * S_ + t] = bkt;
    }
  }
}

// ---------------------------------------------------------------------------
// Kernel 2: stable counting sort per (b,h). Unchanged.
// ---------------------------------------------------------------------------
__global__ __launch_bounds__(1024) void sort_kernel(
    const int* __restrict__ bucket, int* __restrict__ st,
    int* __restrict__ undo)
{
  __shared__ int lb[S_];
  __shared__ int hist[8 * 128];
  __shared__ int off[128];
  const int tid = threadIdx.x;
  const int bh  = blockIdx.x;
  const size_t base = (size_t)bh * S_;

  for (int k = tid; k < S_; k += 1024) lb[k] = bucket[base + k];
  hist[tid] = 0;
  __syncthreads();

  {
    const int seg = tid >> 7;
    const int t0 = tid * 8;
#pragma unroll
    for (int k = 0; k < 8; ++k) atomicAdd(&hist[seg * 128 + lb[t0 + k]], 1);
  }
  __syncthreads();
  if (tid < 128) {
    int s = 0;
#pragma unroll
    for (int g = 0; g < 8; ++g) s += hist[g * 128 + tid];
    off[tid] = s;
  }
  __syncthreads();
  if (tid == 0) {
    int run = 0;
    for (int k = 0; k < 128; ++k) { const int c = off[k]; off[k] = run; run += c; }
  }
  __syncthreads();
  if (tid < 128) {
    int run = off[tid];
#pragma unroll
    for (int g = 0; g < 8; ++g) { const int c = hist[g * 128 + tid]; hist[g * 128 + tid] = run; run += c; }
  }
  __syncthreads();

  const int bkt = tid & 127;
  const int seg = tid >> 7;
  int pos = hist[seg * 128 + bkt];
  const int sbase = seg * 1024;
  const int b = bh >> 3, h = bh & 7;
  const size_t stb = (size_t)b * (H_ * S_) + (size_t)h * S_;
  for (int k = 0; k < 1024; ++k) {
    const int t = sbase + k;
    if (lb[t] == bkt) {
      st[stb + pos] = t;
      undo[base + t] = h * S_ + pos;
      ++pos;
    }
  }
}

// ---------------------------------------------------------------------------
// Kernel 3: bucketed attention via f16 MFMA. Unchanged from R2.
// ---------------------------------------------------------------------------
__global__ __launch_bounds__(256, 4) void attn_kernel(
    const float* __restrict__ qk, const float* __restrict__ v,
    const int* __restrict__ st, float* __restrict__ so,
    float* __restrict__ slogits)
{
  __shared__ _Float16 sQ[64 * 72];    // 9216 B
  __shared__ _Float16 sK[64 * 72];    // 9216 B
  __shared__ _Float16 sP[64 * 136];   // 17408 B
  __shared__ int sIds[128];

  const int tid = threadIdx.x;
  const int c   = blockIdx.x & (NC_ - 1);
  const int b   = blockIdx.x >> 10;
  const int cm1 = (c + NC_ - 1) & (NC_ - 1);
  const size_t bst = (size_t)b * (H_ * S_);
  const size_t row0 = bst + (size_t)c * 64;
  const size_t row1 = bst + (size_t)cm1 * 64;

  const int lane = tid & 63;
  const int w    = tid >> 6;
  const int m16  = lane & 15;
  const int qd   = lane >> 4;

  if (tid < 128) sIds[tid] = (tid < 64) ? st[row0 + tid] : st[row1 + tid - 64];

  const int r  = tid >> 2, qu = tid & 3;
  {
    const int tok = st[row0 + r];
    const f32x4* src = (const f32x4*)(qk + ((size_t)b * S_ + tok) * D_ + qu * 16);
    float x[16];
#pragma unroll
    for (int k = 0; k < 4; ++k) ((f32x4*)x)[k] = src[k];
    float ss = 0.f;
#pragma unroll
    for (int k = 0; k < 16; ++k) ss = fmaf(x[k], x[k], ss);
    ss += __shfl_xor(ss, 1); ss += __shfl_xor(ss, 2);
    const float inv = 0.125f / (sqrtf(ss) + 1e-6f);
    f16x8 raw0, raw1, nrm0, nrm1;
#pragma unroll
    for (int jj = 0; jj < 8; ++jj) {
      raw0[jj] = (_Float16)x[jj];         raw1[jj] = (_Float16)x[jj + 8];
      nrm0[jj] = (_Float16)(x[jj] * inv); nrm1[jj] = (_Float16)(x[jj + 8] * inv);
    }
    *(f16x8*)(sQ + r * 72 + qu * 16)     = raw0;
    *(f16x8*)(sQ + r * 72 + qu * 16 + 8) = raw1;
    *(f16x8*)(sK + r * 72 + qu * 16)     = nrm0;
    *(f16x8*)(sK + r * 72 + qu * 16 + 8) = nrm1;
  }
  __syncthreads();

  f32x4 acc[8];
#pragma unroll
  for (int jt = 0; jt < 8; ++jt) acc[jt] = (f32x4){0.f, 0.f, 0.f, 0.f};

  const _Float16* qrow = sQ + (16 * w + m16) * 72;
  const f16x8 a0 = *(const f16x8*)(qrow + 8 * qd);
  const f16x8 a1 = *(const f16x8*)(qrow + 32 + 8 * qd);

#pragma unroll
  for (int jt = 0; jt < 4; ++jt) {
    const _Float16* krow = sK + (16 * jt + m16) * 72;
    const f16x8 b0 = *(const f16x8*)(krow + 8 * qd);
    const f16x8 b1 = *(const f16x8*)(krow + 32 + 8 * qd);
    acc[jt] = __builtin_amdgcn_mfma_f32_16x16x32_f16(a0, b0, acc[jt], 0, 0, 0);
    acc[jt] = __builtin_amdgcn_mfma_f32_16x16x32_f16(a1, b1, acc[jt], 0, 0, 0);
  }
  __syncthreads();

  {
    const int tok = st[row1 + r];
    const f32x4* src = (const f32x4*)(qk + ((size_t)b * S_ + tok) * D_ + qu * 16);
    float x[16];
#pragma unroll
    for (int k = 0; k < 4; ++k) ((f32x4*)x)[k] = src[k];
    float ss = 0.f;
#pragma unroll
    for (int k = 0; k < 16; ++k) ss = fmaf(x[k], x[k], ss);
    ss += __shfl_xor(ss, 1); ss += __shfl_xor(ss, 2);
    const float inv = 0.125f / (sqrtf(ss) + 1e-6f);
    f16x8 nrm0, nrm1;
#pragma unroll
    for (int jj = 0; jj < 8; ++jj) {
      nrm0[jj] = (_Float16)(x[jj] * inv); nrm1[jj] = (_Float16)(x[jj + 8] * inv);
    }
    *(f16x8*)(sK + r * 72 + qu * 16)     = nrm0;
    *(f16x8*)(sK + r * 72 + qu * 16 + 8) = nrm1;
  }
  __syncthreads();

#pragma unroll
  for (int jt = 4; jt < 8; ++jt) {
    const _Float16* krow = sK + (16 * (jt - 4) + m16) * 72;
    const f16x8 b0 = *(const f16x8*)(krow + 8 * qd);
    const f16x8 b1 = *(const f16x8*)(krow + 32 + 8 * qd);
    acc[jt] = __builtin_amdgcn_mfma_f32_16x16x32_f16(a0, b0, acc[jt], 0, 0, 0);
    acc[jt] = __builtin_amdgcn_mfma_f32_16x16x32_f16(a1, b1, acc[jt], 0, 0, 0);
  }

  const int jp = tid >> 2;
  const int tok0 = sIds[2 * jp], tok1 = sIds[2 * jp + 1];
  f32x4 vr0[4], vr1[4];
  {
    const f32x4* s0 = (const f32x4*)(v + ((size_t)b * S_ + tok0) * D_ + qu * 16);
    const f32x4* s1 = (const f32x4*)(v + ((size_t)b * S_ + tok1) * D_ + qu * 16);
#pragma unroll
    for (int k = 0; k < 4; ++k) { vr0[k] = s0[k]; vr1[k] = s1[k]; }
  }

  int rid[4];
#pragma unroll
  for (int rg = 0; rg < 4; ++rg) rid[rg] = sIds[16 * w + 4 * qd + rg];
  float rmax[4] = {-1e30f, -1e30f, -1e30f, -1e30f};
#pragma unroll
  for (int jt = 0; jt < 8; ++jt) {
    const int cid = sIds[16 * jt + m16];
#pragma unroll
    for (int rg = 0; rg < 4; ++rg) {
      float x = acc[jt][rg];
      if (rid[rg] == cid) x = -5e4f;
      acc[jt][rg] = x;
      rmax[rg] = fmaxf(rmax[rg], x);
    }
  }
#pragma unroll
  for (int rg = 0; rg < 4; ++rg) {
    rmax[rg] = fmaxf(rmax[rg], __shfl_xor(rmax[rg], 1));
    rmax[rg] = fmaxf(rmax[rg], __shfl_xor(rmax[rg], 2));
    rmax[rg] = fmaxf(rmax[rg], __shfl_xor(rmax[rg], 4));
    rmax[rg] = fmaxf(rmax[rg], __shfl_xor(rmax[rg], 8));
  }
  float rsum[4] = {0.f, 0.f, 0.f, 0.f};
#pragma unroll
  for (int jt = 0; jt < 8; ++jt)
#pragma unroll
    for (int rg = 0; rg < 4; ++rg) {
      const float e = __expf(acc[jt][rg] - rmax[rg]);
      acc[jt][rg] = e;
      rsum[rg] += e;
    }
#pragma unroll
  for (int rg = 0; rg < 4; ++rg) {
    rsum[rg] += __shfl_xor(rsum[rg], 1);
    rsum[rg] += __shfl_xor(rsum[rg], 2);
    rsum[rg] += __shfl_xor(rsum[rg], 4);
    rsum[rg] += __shfl_xor(rsum[rg], 8);
  }
  float rinv[4];
#pragma unroll
  for (int rg = 0; rg < 4; ++rg) rinv[rg] = 1.f / rsum[rg];
  if (m16 == 0) {
#pragma unroll
    for (int rg = 0; rg < 4; ++rg)
      slogits[row0 + 16 * w + 4 * qd + rg] = rmax[rg] + __logf(rsum[rg]);
  }

#pragma unroll
  for (int jt = 0; jt < 8; ++jt)
#pragma unroll
    for (int rg = 0; rg < 4; ++rg)
      sP[(16 * w + 4 * qd + rg) * 136 + 16 * jt + m16] = (_Float16)acc[jt][rg];

  __syncthreads();

  {
    const int j = 2 * jp;
    _Float16* dst = (j < 64) ? (sK + (j)) : (sQ + (j - 64));
    float x0[16], x1[16];
#pragma unroll
    for (int k = 0; k < 4; ++k) { ((f32x4*)x0)[k] = vr0[k]; ((f32x4*)x1)[k] = vr1[k]; }
#pragma unroll
    for (int jj = 0; jj < 16; ++jj) {
      const int d = qu * 16 + jj;
      f16x2 pk; pk[0] = (_Float16)x0[jj]; pk[1] = (_Float16)x1[jj];
      *(f16x2*)(dst + d * 72) = pk;
    }
  }
  __syncthreads();

  f32x4 oacc[4];
#pragma unroll
  for (int dt = 0; dt < 4; ++dt) oacc[dt] = (f32x4){0.f, 0.f, 0.f, 0.f};

  const _Float16* prow = sP + (16 * w + m16) * 136;
#pragma unroll
  for (int s = 0; s < 4; ++s) {
    const f16x8 ap = *(const f16x8*)(prow + 32 * s + 8 * qd);
    const _Float16* vbase = (s < 2) ? sK : sQ;
    const int col0 = 32 * (s & 1) + 8 * qd;
#pragma unroll
    for (int dt = 0; dt < 4; ++dt) {
      const f16x8 bv = *(const f16x8*)(vbase + (16 * dt + m16) * 72 + col0);
      oacc[dt] = __builtin_amdgcn_mfma_f32_16x16x32_f16(ap, bv, oacc[dt], 0, 0, 0);
    }
  }

  const size_t ob = row0 * 64;
#pragma unroll
  for (int dt = 0; dt < 4; ++dt)
#pragma unroll
    for (int rg = 0; rg < 4; ++rg) {
      const int i = 16 * w + 4 * qd + rg;
      const int d = 16 * dt + m16;
      so[ob + (size_t)i * 64 + d] = oacc[dt][rg] * rinv[rg];
    }
}

// ---------------------------------------------------------------------------
// Kernel 4: un-sort + combine rounds with logsumexp weights. Unchanged.
// ---------------------------------------------------------------------------
__global__ __launch_bounds__(256) void combine_kernel(
    const float* __restrict__ so, const float* __restrict__ slogits,
    const int* __restrict__ undo, float* __restrict__ out)
{
  const int gt = blockIdx.x * 4 + (threadIdx.x >> 6);
  const int d  = threadIdx.x & 63;
  const int b  = gt >> 13;
  const int t  = gt & (S_ - 1);
  const size_t bst = (size_t)b * (H_ * S_);

  int p[8]; float l[8];
#pragma unroll
  for (int h = 0; h < 8; ++h) {
    p[h] = undo[((size_t)b * 8 + h) * S_ + t];
    l[h] = slogits[bst + p[h]];
  }
  float m = l[0];
#pragma unroll
  for (int h = 1; h < 8; ++h) m = fmaxf(m, l[h]);
  float wv[8], W = 0.f;
#pragma unroll
  for (int h = 0; h < 8; ++h) { wv[h] = expf(l[h] - m); W += wv[h]; }
  const float iW = 1.f / W;
  float acc = 0.f;
#pragma unroll
  for (int h = 0; h < 8; ++h)
    acc = fmaf(wv[h], so[(bst + (size_t)p[h]) * 64 + d], acc);
  out[(size_t)gt * 64 + d] = acc * iW;
}

// ---------------------------------------------------------------------------
extern "C" void kernel_launch(void* const* d_in, const int* in_sizes, int n_in,
                              void* d_out, int out_size, void* d_ws, size_t ws_size,
                              hipStream_t stream)
{
  const float* qk  = (const float*)d_in[0];
  const float* v   = (const float*)d_in[1];
  const float* rot = (const float*)d_in[2];
  float* out = (float*)d_out;

  char* ws = (char*)d_ws;
  const size_t MB = 1ull << 20;
  int*   bucket = (int*)  (ws + 0 * MB);
  int*   st     = (int*)  (ws + 2 * MB);
  int*   undo   = (int*)  (ws + 4 * MB);
  float* slog   = (float*)(ws + 6 * MB);
  float* so     = (float*)(ws + 8 * MB);
  // transient state in the head of the so-region (dead once attn runs):
  int*      cnt    = (int*)      (ws + 8 * MB);
  int2*     list   = (int2*)     (ws + 8 * MB + 256);
  _Float16* rotHi  = (_Float16*) (ws + 9 * MB);            // 8*64*64 f16 = 64 KB
  _Float16* rotLo  = (_Float16*) (ws + 9 * MB + 65536);
  if (ws_size < 136 * MB) return;

  hipLaunchKernelGGL(prep_kernel,    dim3(8),           dim3(256),  0, stream, rot, rotHi, rotLo, cnt);
  hipLaunchKernelGGL(hash_kernel,    dim3(64 * 128),    dim3(256),  0, stream, qk, rotHi, rotLo, bucket, cnt, list);
  hipLaunchKernelGGL(repair_kernel,  dim3(128),         dim3(256),  0, stream, qk, rot, cnt, list, bucket);
  hipLaunchKernelGGL(sort_kernel,    dim3(64),          dim3(1024), 0, stream, bucket, st, undo);
  hipLaunchKernelGGL(attn_kernel,    dim3(B_ * NC_),    dim3(256),  0, stream, qk, v, st, so, slog);
  hipLaunchKernelGGL(combine_kernel, dim3(B_ * S_ / 4), dim3(256),  0, stream, so, slog, undo, out);
}